// Round 1
// baseline (274.537 us; speedup 1.0000x reference)
//
#include <hip/hip_runtime.h>

#define BB 16
#define SS 2048
#define DD 128

typedef __attribute__((ext_vector_type(4))) float f32x4;
typedef __attribute__((ext_vector_type(8))) short short8;
typedef __attribute__((ext_vector_type(4))) unsigned short us4;
typedef __attribute__((ext_vector_type(8))) unsigned short us8;

__device__ inline unsigned short f2bf(float f) {
    unsigned u = __float_as_uint(f);
    u += 0x7fffu + ((u >> 16) & 1u);   // round-to-nearest-even
    return (unsigned short)(u >> 16);
}

// XOR swizzle for bf16 LDS tiles (breaks the row-major 32-way bank conflict, G4)
__device__ inline int swzA(int row, int col) { // 128-col bf16 tile (256B rows)
    int byteoff = (row << 8) + ((col >> 3) << 4);
    byteoff ^= (row & 7) << 4;
    return (byteoff >> 1) + (col & 7);
}
__device__ inline int swzB(int row, int col) { // 64-col bf16 tile (128B rows)
    int byteoff = (row << 7) + ((col >> 3) << 4);
    byteoff ^= (row & 7) << 4;
    return (byteoff >> 1) + (col & 7);
}

// ---------------------------------------------------------------------------
// Kernel A: P = mask ? exp(Q K^T / sqrt(D)) : 0   (unnormalized, fp32)
// grid (S/128, S/128, B), block 256 (4 waves, each 64x64 via 4x4 16x16x32 MFMA)
// ---------------------------------------------------------------------------
__global__ __launch_bounds__(256) void qk_exp_kernel(
    const float* __restrict__ Q, const float* __restrict__ Kin,
    const int* __restrict__ mask, float* __restrict__ P)
{
    __shared__ unsigned short Qs[128 * 128];
    __shared__ unsigned short Ks[128 * 128];
    const int b  = blockIdx.z;
    const int m0 = blockIdx.y << 7;
    const int n0 = blockIdx.x << 7;
    const int t  = threadIdx.x;
    const float* Qp = Q   + ((size_t)b * SS + m0) * DD;
    const float* Kp = Kin + ((size_t)b * SS + n0) * DD;

    // stage 128x128 fp32 -> bf16 LDS (tiles are contiguous: row stride == D)
    for (int i = 0; i < 16; ++i) {
        int f4  = (i << 8) + t;
        int row = f4 >> 5;
        int col = (f4 & 31) << 2;
        f32x4 q = reinterpret_cast<const f32x4*>(Qp)[f4];
        f32x4 k = reinterpret_cast<const f32x4*>(Kp)[f4];
        us4 qh, kh;
        for (int j = 0; j < 4; ++j) { qh[j] = f2bf(q[j]); kh[j] = f2bf(k[j]); }
        *reinterpret_cast<us4*>(&Qs[swzA(row, col)]) = qh;
        *reinterpret_cast<us4*>(&Ks[swzA(row, col)]) = kh;
    }
    __syncthreads();

    const int lane = t & 63, wid = t >> 6;
    const int wr = wid >> 1, wc = wid & 1;
    const int lr = lane & 15, lg = lane >> 4;

    f32x4 acc[4][4] = {};
    for (int kb = 0; kb < 4; ++kb) {
        short8 a[4], bq[4];
        int kcol = (kb << 5) + (lg << 3);
        for (int m = 0; m < 4; ++m)
            a[m] = *reinterpret_cast<const short8*>(&Qs[swzA((wr << 6) + (m << 4) + lr, kcol)]);
        for (int n = 0; n < 4; ++n)
            bq[n] = *reinterpret_cast<const short8*>(&Ks[swzA((wc << 6) + (n << 4) + lr, kcol)]);
        for (int m = 0; m < 4; ++m)
            for (int n = 0; n < 4; ++n)
                acc[m][n] = __builtin_amdgcn_mfma_f32_16x16x32_bf16(a[m], bq[n], acc[m][n], 0, 0, 0);
    }

    const float inv_scale = 0.08838834764831845f; // 1/sqrt(128)
    const int* am = mask + (size_t)b * SS;
    for (int n = 0; n < 4; ++n) {
        int col = n0 + (wc << 6) + (n << 4) + lr;
        bool allow = am[col] != 0;
        for (int m = 0; m < 4; ++m) {
            int rowb = m0 + (wr << 6) + (m << 4) + (lg << 2);
            float* Pp = P + ((size_t)b * SS + rowb) * SS + col;
            for (int r = 0; r < 4; ++r) {
                float p = allow ? __expf(acc[m][n][r] * inv_scale) : 0.0f;
                Pp[(size_t)r * SS] = p;
            }
        }
    }
}

// ---------------------------------------------------------------------------
// Kernel B: in-place row normalization (softmax denominator).
// One wave per row. sum==0 (no allowed keys) -> zero row (matches reference).
// ---------------------------------------------------------------------------
__global__ __launch_bounds__(256) void norm_kernel(float* __restrict__ P)
{
    int row  = (blockIdx.x << 2) + (threadIdx.x >> 6);
    int lane = threadIdx.x & 63;
    float* Pr = P + (size_t)row * SS;
    f32x4 v[8];
    float sum = 0.f;
    for (int i = 0; i < 8; ++i) {
        v[i] = reinterpret_cast<f32x4*>(Pr)[(i << 6) + lane];
        sum += v[i][0] + v[i][1] + v[i][2] + v[i][3];
    }
    for (int off = 1; off < 64; off <<= 1) sum += __shfl_xor(sum, off, 64);
    float inv = sum > 0.f ? 1.f / sum : 0.f;
    for (int i = 0; i < 8; ++i) {
        f32x4 w = v[i];
        for (int j = 0; j < 4; ++j) w[j] *= inv;
        reinterpret_cast<f32x4*>(Pr)[(i << 6) + lane] = w;
    }
}

// ---------------------------------------------------------------------------
// Kernel Vt: V (b,k,n) fp32 -> VT (b,n,k) bf16 in workspace
// grid (S/64, B), block 256. LDS tile transpose, padded stride 136.
// ---------------------------------------------------------------------------
__global__ __launch_bounds__(256) void vt_kernel(
    const float* __restrict__ V, unsigned short* __restrict__ VT)
{
    __shared__ unsigned short tile[64 * 136];
    int b = blockIdx.y, k0 = blockIdx.x << 6;
    int t = threadIdx.x;
    const float* Vg = V + ((size_t)b * SS + k0) * DD;
    for (int i = 0; i < 8; ++i) {
        int f4 = (i << 8) + t;
        int k  = f4 >> 5;
        int n  = (f4 & 31) << 2;
        f32x4 v = reinterpret_cast<const f32x4*>(Vg)[f4];
        us4 h;
        for (int j = 0; j < 4; ++j) h[j] = f2bf(v[j]);
        *reinterpret_cast<us4*>(&tile[k * 136 + n]) = h;
    }
    __syncthreads();
    unsigned short* outp = VT + (size_t)b * DD * SS;
    for (int i = 0; i < 4; ++i) {
        int id = (i << 8) + t;
        int n  = id >> 3;
        int c8 = id & 7;
        us8 o;
        for (int j = 0; j < 8; ++j) o[j] = tile[((c8 << 3) + j) * 136 + n];
        *reinterpret_cast<us8*>(&outp[(size_t)n * SS + k0 + (c8 << 3)]) = o;
    }
}

// ---------------------------------------------------------------------------
// Kernel C: O = W * V   (W = normalized attn weights, fp32 -> bf16 on the fly)
// grid (S/64, B), block 256 (4 waves: 2x2, each 32x64). BK=64.
// USE_WS: B-operand from bf16 V^T in workspace (fast). Else strided global.
// ---------------------------------------------------------------------------
template<bool USE_WS>
__global__ __launch_bounds__(256) void pv_kernel(
    const float* __restrict__ P, const float* __restrict__ V,
    const unsigned short* __restrict__ VT, float* __restrict__ O)
{
    __shared__ unsigned short Ws[64 * 64];
    __shared__ unsigned short Vs[128 * 64];
    const int b  = blockIdx.y;
    const int m0 = blockIdx.x << 6;
    const int t  = threadIdx.x, lane = t & 63, wid = t >> 6;
    const int wr = wid >> 1, wc = wid & 1;
    const int lr = lane & 15, lg = lane >> 4;
    const float* Pg = P + ((size_t)b * SS + m0) * SS;
    f32x4 acc[2][4] = {};

    for (int k0 = 0; k0 < SS; k0 += 64) {
        __syncthreads();
        // stage W tile 64x64 fp32 -> bf16
        for (int i = 0; i < 4; ++i) {
            int f4  = (i << 8) + t;
            int row = f4 >> 4;
            int col = (f4 & 15) << 2;
            f32x4 w = *reinterpret_cast<const f32x4*>(Pg + (size_t)row * SS + k0 + col);
            us4 h;
            for (int j = 0; j < 4; ++j) h[j] = f2bf(w[j]);
            *reinterpret_cast<us4*>(&Ws[swzB(row, col)]) = h;
        }
        if (USE_WS) {
            const unsigned short* Vt = VT + (size_t)b * DD * SS;
            for (int i = 0; i < 4; ++i) {
                int id  = (i << 8) + t;
                int row = id >> 3;
                int col = (id & 7) << 3;
                us8 v = *reinterpret_cast<const us8*>(&Vt[(size_t)row * SS + k0 + col]);
                *reinterpret_cast<us8*>(&Vs[swzB(row, col)]) = v;
            }
        }
        __syncthreads();

        for (int kk = 0; kk < 64; kk += 32) {
            short8 a[2], bv[4];
            int kcol = kk + (lg << 3);
            for (int m = 0; m < 2; ++m)
                a[m] = *reinterpret_cast<const short8*>(&Ws[swzB((wr << 5) + (m << 4) + lr, kcol)]);
            if (USE_WS) {
                for (int n = 0; n < 4; ++n)
                    bv[n] = *reinterpret_cast<const short8*>(&Vs[swzB((wc << 6) + (n << 4) + lr, kcol)]);
            } else {
                for (int n = 0; n < 4; ++n) {
                    int col = (wc << 6) + (n << 4) + lr;
                    const float* vp = V + ((size_t)b * SS + k0 + kcol) * DD + col;
                    short8 x;
                    for (int j = 0; j < 8; ++j) x[j] = (short)f2bf(vp[(size_t)j * DD]);
                    bv[n] = x;
                }
            }
            for (int m = 0; m < 2; ++m)
                for (int n = 0; n < 4; ++n)
                    acc[m][n] = __builtin_amdgcn_mfma_f32_16x16x32_bf16(a[m], bv[n], acc[m][n], 0, 0, 0);
        }
    }

    float* Og = O + ((size_t)b * SS + m0) * DD;
    for (int m = 0; m < 2; ++m)
        for (int n = 0; n < 4; ++n)
            for (int r = 0; r < 4; ++r)
                Og[(size_t)((wr << 5) + (m << 4) + (lg << 2) + r) * DD
                   + (wc << 6) + (n << 4) + lr] = acc[m][n][r];
}

// ---------------------------------------------------------------------------
extern "C" void kernel_launch(void* const* d_in, const int* in_sizes, int n_in,
                              void* d_out, int out_size, void* d_ws, size_t ws_size,
                              hipStream_t stream)
{
    const float* Q   = (const float*)d_in[0];
    const float* K   = (const float*)d_in[1];
    const float* V   = (const float*)d_in[2];
    const int* mask  = (const int*)d_in[3];
    float* O = (float*)d_out;
    float* P = O + (size_t)BB * SS * DD;   // attn_weights region (output 1)

    qk_exp_kernel<<<dim3(SS / 128, SS / 128, BB), 256, 0, stream>>>(Q, K, mask, P);
    norm_kernel<<<(BB * SS) / 4, 256, 0, stream>>>(P);

    size_t vt_bytes = (size_t)BB * DD * SS * sizeof(unsigned short); // 8 MB
    if (ws_size >= vt_bytes) {
        unsigned short* VT = (unsigned short*)d_ws;
        vt_kernel<<<dim3(SS / 64, BB), 256, 0, stream>>>(V, VT);
        pv_kernel<true><<<dim3(SS / 64, BB), 256, 0, stream>>>(P, V, VT, O);
    } else {
        pv_kernel<false><<<dim3(SS / 64, BB), 256, 0, stream>>>(P, V, nullptr, O);
    }
}

// Round 2
// 230.120 us; speedup vs baseline: 1.1930x; 1.1930x over previous
//
#include <hip/hip_runtime.h>

#define BB 16
#define SS 2048
#define DD 128

typedef __attribute__((ext_vector_type(4))) float f32x4;
typedef __attribute__((ext_vector_type(8))) short short8;
typedef __attribute__((ext_vector_type(4))) unsigned short us4;
typedef __attribute__((ext_vector_type(8))) unsigned short us8;

#define INVSCALE 0.08838834764831845f  // 1/sqrt(128)

__device__ inline unsigned short f2bf(float f) {
    unsigned u = __float_as_uint(f);
    u += 0x7fffu + ((u >> 16) & 1u);   // round-to-nearest-even
    return (unsigned short)(u >> 16);
}

// XOR swizzle for bf16 LDS tiles (breaks row-major D=128 32-way bank conflict)
__device__ inline int swzA(int row, int col) { // 128-col bf16 tile (256B rows)
    int byteoff = (row << 8) + ((col >> 3) << 4);
    byteoff ^= (row & 7) << 4;
    return (byteoff >> 1) + (col & 7);
}
__device__ inline int swzB(int row, int col) { // 64-col bf16 tile (128B rows)
    int byteoff = (row << 7) + ((col >> 3) << 4);
    byteoff ^= (row & 7) << 4;
    return (byteoff >> 1) + (col & 7);
}

// ---------------------------------------------------------------------------
// conv: Q,K fp32 -> bf16 (contiguous)
// ---------------------------------------------------------------------------
__global__ __launch_bounds__(256) void conv_bf16_kernel(
    const float* __restrict__ Q, const float* __restrict__ K,
    unsigned short* __restrict__ Qb, unsigned short* __restrict__ Kb)
{
    int idx = blockIdx.x * blockDim.x + threadIdx.x;
    const int total = BB * SS * DD / 4;
    for (int i = idx; i < total; i += gridDim.x * blockDim.x) {
        f32x4 q = reinterpret_cast<const f32x4*>(Q)[i];
        f32x4 k = reinterpret_cast<const f32x4*>(K)[i];
        us4 qh, kh;
        for (int j = 0; j < 4; ++j) { qh[j] = f2bf(q[j]); kh[j] = f2bf(k[j]); }
        reinterpret_cast<us4*>(Qb)[i] = qh;
        reinterpret_cast<us4*>(Kb)[i] = kh;
    }
}

// ---------------------------------------------------------------------------
// Vt: V (b,k,d) fp32 -> VT (b,d,k) bf16 in workspace
// ---------------------------------------------------------------------------
__global__ __launch_bounds__(256) void vt_kernel(
    const float* __restrict__ V, unsigned short* __restrict__ VT)
{
    __shared__ unsigned short tile[64 * 136];
    int b = blockIdx.y, k0 = blockIdx.x << 6;
    int t = threadIdx.x;
    const float* Vg = V + ((size_t)b * SS + k0) * DD;
    for (int i = 0; i < 8; ++i) {
        int f4 = (i << 8) + t;
        int k  = f4 >> 5;
        int n  = (f4 & 31) << 2;
        f32x4 v = reinterpret_cast<const f32x4*>(Vg)[f4];
        us4 h;
        for (int j = 0; j < 4; ++j) h[j] = f2bf(v[j]);
        *reinterpret_cast<us4*>(&tile[k * 136 + n]) = h;
    }
    __syncthreads();
    unsigned short* outp = VT + (size_t)b * DD * SS;
    for (int i = 0; i < 4; ++i) {
        int id = (i << 8) + t;
        int n  = id >> 3;
        int c8 = id & 7;
        us8 o;
        for (int j = 0; j < 8; ++j) o[j] = tile[((c8 << 3) + j) * 136 + n];
        *reinterpret_cast<us8*>(&outp[(size_t)n * SS + k0 + (c8 << 3)]) = o;
    }
}

// ---------------------------------------------------------------------------
// flash: per 128-row block, stream KV tiles (128): S=QK^T, p=mask?exp:0,
// accumulate rowsum L and O += P*V (P routed through per-wave LDS tile).
// Writes O = O/L and invL. grid (S/128, B), 256 threads (4 waves x 32 rows).
// ---------------------------------------------------------------------------
__global__ __launch_bounds__(256, 1) void flash_kernel(
    const unsigned short* __restrict__ Qb, const unsigned short* __restrict__ Kb,
    const unsigned short* __restrict__ VT, const int* __restrict__ mask,
    float* __restrict__ O, float* __restrict__ invL)
{
    __shared__ unsigned short Ks[128 * 128];
    __shared__ unsigned short Vts[128 * 128];
    __shared__ unsigned short Ps[4 * 32 * 128];
    const int b = blockIdx.y, m0 = blockIdx.x << 7;
    const int t = threadIdx.x, lane = t & 63, w = t >> 6;
    const int lr = lane & 15, lg = lane >> 4;
    const unsigned short* Qp = Qb + ((size_t)b * SS + m0) * DD;
    const unsigned short* Kp = Kb + (size_t)b * SS * DD;
    const unsigned short* Vp = VT + (size_t)b * DD * SS;
    const int* mb = mask + (size_t)b * SS;

    // Q fragments in registers: rows w*32 + mf*16 + lr
    short8 aq[2][4];
    for (int mf = 0; mf < 2; ++mf)
        for (int kb = 0; kb < 4; ++kb)
            aq[mf][kb] = *reinterpret_cast<const short8*>(
                Qp + (size_t)(w * 32 + mf * 16 + lr) * DD + kb * 32 + lg * 8);

    f32x4 oacc[2][8] = {};
    f32x4 rsum[2] = {};

    for (int kv0 = 0; kv0 < SS; kv0 += 128) {
        __syncthreads();   // prev iteration's PV reads done before restage
        for (int i = 0; i < 8; ++i) {
            int id  = (i << 8) + t;
            int row = id >> 4;
            int col = (id & 15) << 3;
            us8 kv = *reinterpret_cast<const us8*>(Kp + (size_t)(kv0 + row) * DD + col);
            *reinterpret_cast<us8*>(&Ks[swzA(row, col)]) = kv;
            us8 vv = *reinterpret_cast<const us8*>(Vp + (size_t)row * SS + kv0 + col);
            *reinterpret_cast<us8*>(&Vts[swzA(row, col)]) = vv;
        }
        __syncthreads();

        // S = Q K^T  (per wave: 32 x 128)
        f32x4 sacc[2][8] = {};
        for (int kb = 0; kb < 4; ++kb) {
            short8 bk[8];
            for (int n = 0; n < 8; ++n)
                bk[n] = *reinterpret_cast<const short8*>(&Ks[swzA(n * 16 + lr, kb * 32 + lg * 8)]);
            for (int mf = 0; mf < 2; ++mf)
                for (int n = 0; n < 8; ++n)
                    sacc[mf][n] = __builtin_amdgcn_mfma_f32_16x16x32_bf16(
                        aq[mf][kb], bk[n], sacc[mf][n], 0, 0, 0);
        }

        // p = mask ? exp(s/scale) : 0 ; rowsum ; stash bf16 P tile in LDS
        unsigned short* Pw = &Ps[w * 4096];
        for (int n = 0; n < 8; ++n) {
            bool allow = mb[kv0 + n * 16 + lr] != 0;
            for (int mf = 0; mf < 2; ++mf)
                for (int r = 0; r < 4; ++r) {
                    float p = allow ? __expf(sacc[mf][n][r] * INVSCALE) : 0.0f;
                    rsum[mf][r] += p;
                    Pw[swzA(mf * 16 + lg * 4 + r, n * 16 + lr)] = f2bf(p);
                }
        }
        asm volatile("s_waitcnt lgkmcnt(0)" ::: "memory");
        __builtin_amdgcn_sched_barrier(0);

        // O += P * V  (wave-local P tile; V^T staged d-major)
        for (int kb2 = 0; kb2 < 4; ++kb2) {
            short8 pa[2];
            for (int mf = 0; mf < 2; ++mf)
                pa[mf] = *reinterpret_cast<const short8*>(&Pw[swzA(mf * 16 + lr, kb2 * 32 + lg * 8)]);
            for (int n = 0; n < 8; ++n) {
                short8 bv = *reinterpret_cast<const short8*>(&Vts[swzA(n * 16 + lr, kb2 * 32 + lg * 8)]);
                for (int mf = 0; mf < 2; ++mf)
                    oacc[mf][n] = __builtin_amdgcn_mfma_f32_16x16x32_bf16(
                        pa[mf], bv, oacc[mf][n], 0, 0, 0);
            }
        }
    }

    // reduce row sums across the 16 lanes of each lg-group
    for (int mf = 0; mf < 2; ++mf)
        for (int off = 1; off < 16; off <<= 1)
            for (int r = 0; r < 4; ++r)
                rsum[mf][r] += __shfl_xor(rsum[mf][r], off, 64);

    float* Og  = O + ((size_t)b * SS + m0 + w * 32) * DD;
    float* iLp = invL + (size_t)b * SS + m0 + w * 32;
    for (int mf = 0; mf < 2; ++mf) {
        f32x4 inv;
        for (int r = 0; r < 4; ++r) inv[r] = rsum[mf][r] > 0.f ? 1.f / rsum[mf][r] : 0.f;
        if (lr == 0)
            for (int r = 0; r < 4; ++r) iLp[mf * 16 + lg * 4 + r] = inv[r];
        for (int n = 0; n < 8; ++n)
            for (int r = 0; r < 4; ++r)
                Og[(size_t)(mf * 16 + lg * 4 + r) * DD + n * 16 + lr] = oacc[mf][n][r] * inv[r];
    }
}

// ---------------------------------------------------------------------------
// p_store: recompute S = Q K^T (bit-identical), write P = mask?exp*invL:0.
// grid (S/128, S/128, B), 256 threads (4 waves, 64x64 each).
// ---------------------------------------------------------------------------
__global__ __launch_bounds__(256, 2) void p_store_kernel(
    const unsigned short* __restrict__ Qb, const unsigned short* __restrict__ Kb,
    const int* __restrict__ mask, const float* __restrict__ invL,
    float* __restrict__ P)
{
    __shared__ unsigned short Qs[128 * 128];
    __shared__ unsigned short Ks[128 * 128];
    const int b = blockIdx.z, m0 = blockIdx.y << 7, n0 = blockIdx.x << 7;
    const int t = threadIdx.x;
    const unsigned short* Qp = Qb + ((size_t)b * SS + m0) * DD;
    const unsigned short* Kp = Kb + ((size_t)b * SS + n0) * DD;
    for (int i = 0; i < 8; ++i) {
        int id  = (i << 8) + t;
        int row = id >> 4;
        int col = (id & 15) << 3;
        *reinterpret_cast<us8*>(&Qs[swzA(row, col)]) =
            *reinterpret_cast<const us8*>(Qp + (size_t)row * DD + col);
        *reinterpret_cast<us8*>(&Ks[swzA(row, col)]) =
            *reinterpret_cast<const us8*>(Kp + (size_t)row * DD + col);
    }
    __syncthreads();

    const int lane = t & 63, wid = t >> 6;
    const int wr = wid >> 1, wc = wid & 1;
    const int lr = lane & 15, lg = lane >> 4;

    f32x4 acc[4][4] = {};
    for (int kb = 0; kb < 4; ++kb) {
        short8 a[4], bq[4];
        int kcol = (kb << 5) + (lg << 3);
        for (int m = 0; m < 4; ++m)
            a[m] = *reinterpret_cast<const short8*>(&Qs[swzA((wr << 6) + (m << 4) + lr, kcol)]);
        for (int n = 0; n < 4; ++n)
            bq[n] = *reinterpret_cast<const short8*>(&Ks[swzA((wc << 6) + (n << 4) + lr, kcol)]);
        for (int m = 0; m < 4; ++m)
            for (int n = 0; n < 4; ++n)
                acc[m][n] = __builtin_amdgcn_mfma_f32_16x16x32_bf16(a[m], bq[n], acc[m][n], 0, 0, 0);
    }

    const int* am = mask + (size_t)b * SS;
    const float* iL = invL + (size_t)b * SS + m0;
    f32x4 ilv[4];
    for (int m = 0; m < 4; ++m)
        ilv[m] = *reinterpret_cast<const f32x4*>(iL + (wr << 6) + (m << 4) + (lg << 2));
    for (int n = 0; n < 4; ++n) {
        int col = n0 + (wc << 6) + (n << 4) + lr;
        bool allow = am[col] != 0;
        for (int m = 0; m < 4; ++m) {
            int rowb = (wr << 6) + (m << 4) + (lg << 2);
            float* Pp = P + ((size_t)b * SS + m0 + rowb) * SS + col;
            for (int r = 0; r < 4; ++r) {
                float p = allow ? __expf(acc[m][n][r] * INVSCALE) * ilv[m][r] : 0.0f;
                Pp[(size_t)r * SS] = p;
            }
        }
    }
}

// ---------------------------------------------------------------------------
// Round-1 fallback kernels (used only if ws_size is too small)
// ---------------------------------------------------------------------------
__global__ __launch_bounds__(256) void qk_exp_kernel(
    const float* __restrict__ Q, const float* __restrict__ Kin,
    const int* __restrict__ mask, float* __restrict__ P)
{
    __shared__ unsigned short Qs[128 * 128];
    __shared__ unsigned short Ks[128 * 128];
    const int b  = blockIdx.z;
    const int m0 = blockIdx.y << 7;
    const int n0 = blockIdx.x << 7;
    const int t  = threadIdx.x;
    const float* Qp = Q   + ((size_t)b * SS + m0) * DD;
    const float* Kp = Kin + ((size_t)b * SS + n0) * DD;
    for (int i = 0; i < 16; ++i) {
        int f4  = (i << 8) + t;
        int row = f4 >> 5;
        int col = (f4 & 31) << 2;
        f32x4 q = reinterpret_cast<const f32x4*>(Qp)[f4];
        f32x4 k = reinterpret_cast<const f32x4*>(Kp)[f4];
        us4 qh, kh;
        for (int j = 0; j < 4; ++j) { qh[j] = f2bf(q[j]); kh[j] = f2bf(k[j]); }
        *reinterpret_cast<us4*>(&Qs[swzA(row, col)]) = qh;
        *reinterpret_cast<us4*>(&Ks[swzA(row, col)]) = kh;
    }
    __syncthreads();
    const int lane = t & 63, wid = t >> 6;
    const int wr = wid >> 1, wc = wid & 1;
    const int lr = lane & 15, lg = lane >> 4;
    f32x4 acc[4][4] = {};
    for (int kb = 0; kb < 4; ++kb) {
        short8 a[4], bq[4];
        int kcol = (kb << 5) + (lg << 3);
        for (int m = 0; m < 4; ++m)
            a[m] = *reinterpret_cast<const short8*>(&Qs[swzA((wr << 6) + (m << 4) + lr, kcol)]);
        for (int n = 0; n < 4; ++n)
            bq[n] = *reinterpret_cast<const short8*>(&Ks[swzA((wc << 6) + (n << 4) + lr, kcol)]);
        for (int m = 0; m < 4; ++m)
            for (int n = 0; n < 4; ++n)
                acc[m][n] = __builtin_amdgcn_mfma_f32_16x16x32_bf16(a[m], bq[n], acc[m][n], 0, 0, 0);
    }
    const int* am = mask + (size_t)b * SS;
    for (int n = 0; n < 4; ++n) {
        int col = n0 + (wc << 6) + (n << 4) + lr;
        bool allow = am[col] != 0;
        for (int m = 0; m < 4; ++m) {
            int rowb = m0 + (wr << 6) + (m << 4) + (lg << 2);
            float* Pp = P + ((size_t)b * SS + rowb) * SS + col;
            for (int r = 0; r < 4; ++r) {
                float p = allow ? __expf(acc[m][n][r] * INVSCALE) : 0.0f;
                Pp[(size_t)r * SS] = p;
            }
        }
    }
}

__global__ __launch_bounds__(256) void norm_kernel(float* __restrict__ P)
{
    int row  = (blockIdx.x << 2) + (threadIdx.x >> 6);
    int lane = threadIdx.x & 63;
    float* Pr = P + (size_t)row * SS;
    f32x4 v[8];
    float sum = 0.f;
    for (int i = 0; i < 8; ++i) {
        v[i] = reinterpret_cast<f32x4*>(Pr)[(i << 6) + lane];
        sum += v[i][0] + v[i][1] + v[i][2] + v[i][3];
    }
    for (int off = 1; off < 64; off <<= 1) sum += __shfl_xor(sum, off, 64);
    float inv = sum > 0.f ? 1.f / sum : 0.f;
    for (int i = 0; i < 8; ++i) {
        f32x4 wv = v[i];
        for (int j = 0; j < 4; ++j) wv[j] *= inv;
        reinterpret_cast<f32x4*>(Pr)[(i << 6) + lane] = wv;
    }
}

__global__ __launch_bounds__(256) void pv_fallback_kernel(
    const float* __restrict__ P, const float* __restrict__ V, float* __restrict__ O)
{
    __shared__ unsigned short Ws[64 * 64];
    const int b  = blockIdx.y;
    const int m0 = blockIdx.x << 6;
    const int t  = threadIdx.x, lane = t & 63, wid = t >> 6;
    const int wr = wid >> 1, wc = wid & 1;
    const int lr = lane & 15, lg = lane >> 4;
    const float* Pg = P + ((size_t)b * SS + m0) * SS;
    f32x4 acc[2][4] = {};
    for (int k0 = 0; k0 < SS; k0 += 64) {
        __syncthreads();
        for (int i = 0; i < 4; ++i) {
            int f4  = (i << 8) + t;
            int row = f4 >> 4;
            int col = (f4 & 15) << 2;
            f32x4 wv = *reinterpret_cast<const f32x4*>(Pg + (size_t)row * SS + k0 + col);
            us4 h;
            for (int j = 0; j < 4; ++j) h[j] = f2bf(wv[j]);
            *reinterpret_cast<us4*>(&Ws[swzB(row, col)]) = h;
        }
        __syncthreads();
        for (int kk = 0; kk < 64; kk += 32) {
            short8 a[2], bv[4];
            int kcol = kk + (lg << 3);
            for (int m = 0; m < 2; ++m)
                a[m] = *reinterpret_cast<const short8*>(&Ws[swzB((wr << 5) + (m << 4) + lr, kcol)]);
            for (int n = 0; n < 4; ++n) {
                int col = (wc << 6) + (n << 4) + lr;
                const float* vp = V + ((size_t)b * SS + k0 + kcol) * DD + col;
                short8 x;
                for (int j = 0; j < 8; ++j) x[j] = (short)f2bf(vp[(size_t)j * DD]);
                bv[n] = x;
            }
            for (int m = 0; m < 2; ++m)
                for (int n = 0; n < 4; ++n)
                    acc[m][n] = __builtin_amdgcn_mfma_f32_16x16x32_bf16(a[m], bv[n], acc[m][n], 0, 0, 0);
        }
    }
    float* Og = O + ((size_t)b * SS + m0) * DD;
    for (int m = 0; m < 2; ++m)
        for (int n = 0; n < 4; ++n)
            for (int r = 0; r < 4; ++r)
                Og[(size_t)((wr << 5) + (m << 4) + (lg << 2) + r) * DD
                   + (wc << 6) + (n << 4) + lr] = acc[m][n][r];
}

// ---------------------------------------------------------------------------
extern "C" void kernel_launch(void* const* d_in, const int* in_sizes, int n_in,
                              void* d_out, int out_size, void* d_ws, size_t ws_size,
                              hipStream_t stream)
{
    const float* Q  = (const float*)d_in[0];
    const float* K  = (const float*)d_in[1];
    const float* V  = (const float*)d_in[2];
    const int* mask = (const int*)d_in[3];
    float* O = (float*)d_out;
    float* P = O + (size_t)BB * SS * DD;

    const size_t nQ = (size_t)BB * SS * DD;          // elements per tensor
    const size_t need = 3 * nQ * sizeof(unsigned short) + (size_t)BB * SS * sizeof(float);

    if (ws_size >= need) {
        unsigned short* Qbf = (unsigned short*)d_ws;
        unsigned short* Kbf = Qbf + nQ;
        unsigned short* VT  = Kbf + nQ;
        float* invL = (float*)(VT + nQ);

        conv_bf16_kernel<<<1024, 256, 0, stream>>>(Q, K, Qbf, Kbf);
        vt_kernel<<<dim3(SS / 64, BB), 256, 0, stream>>>(V, VT);
        flash_kernel<<<dim3(SS / 128, BB), 256, 0, stream>>>(Qbf, Kbf, VT, mask, O, invL);
        p_store_kernel<<<dim3(SS / 128, SS / 128, BB), 256, 0, stream>>>(Qbf, Kbf, mask, invL, P);
    } else {
        // fallback: round-1 pipeline (no workspace requirements)
        qk_exp_kernel<<<dim3(SS / 128, SS / 128, BB), 256, 0, stream>>>(Q, K, mask, P);
        norm_kernel<<<(BB * SS) / 4, 256, 0, stream>>>(P);
        pv_fallback_kernel<<<dim3(SS / 64, BB), 256, 0, stream>>>(P, V, O);
    }
}

// Round 3
// 181.445 us; speedup vs baseline: 1.5131x; 1.2683x over previous
//
#include <hip/hip_runtime.h>

#define BB 16
#define SS 2048
#define DD 128
#define NT (SS / 128)                  // 16 KV tiles of 128
#define INVSCALE 0.08838834764831845f  // 1/sqrt(128)

typedef __attribute__((ext_vector_type(4))) float f32x4;
typedef __attribute__((ext_vector_type(8))) short short8;
typedef __attribute__((ext_vector_type(4))) unsigned short us4;
typedef __attribute__((ext_vector_type(8))) unsigned short us8;

__device__ inline unsigned short f2bf(float f) {
    unsigned u = __float_as_uint(f);
    u += 0x7fffu + ((u >> 16) & 1u);   // round-to-nearest-even
    return (unsigned short)(u >> 16);
}

// XOR swizzle for bf16 LDS tiles with 128-col (256 B) rows
__device__ inline int swzA(int row, int col) {
    int byteoff = (row << 8) + ((col >> 3) << 4);
    byteoff ^= (row & 7) << 4;
    return (byteoff >> 1) + (col & 7);
}
__device__ inline int swzB(int row, int col) { // 64-col (128 B) rows (fallback kernels)
    int byteoff = (row << 7) + ((col >> 3) << 4);
    byteoff ^= (row & 7) << 4;
    return (byteoff >> 1) + (col & 7);
}

// ---------------------------------------------------------------------------
// vt: V (b,k,d) fp32 -> VT (b,d,k) bf16 with masked k zeroed; maskbf (b,k) bf16
// ---------------------------------------------------------------------------
__global__ __launch_bounds__(256) void vt_kernel(
    const float* __restrict__ V, const int* __restrict__ mask,
    unsigned short* __restrict__ VT, unsigned short* __restrict__ maskbf)
{
    __shared__ unsigned short tile[64 * 136];
    int b = blockIdx.y, k0 = blockIdx.x << 6;
    int t = threadIdx.x;
    const float* Vg = V + ((size_t)b * SS + k0) * DD;
    const int* am = mask + (size_t)b * SS;
    for (int i = 0; i < 8; ++i) {
        int f4 = (i << 8) + t;
        int k  = f4 >> 5;
        int n  = (f4 & 31) << 2;
        f32x4 v = reinterpret_cast<const f32x4*>(Vg)[f4];
        float mf = am[k0 + k] ? 1.0f : 0.0f;
        us4 h;
        for (int j = 0; j < 4; ++j) h[j] = f2bf(v[j] * mf);
        *reinterpret_cast<us4*>(&tile[k * 136 + n]) = h;
    }
    if (t < 64)
        maskbf[(size_t)b * SS + k0 + t] = am[k0 + t] ? (unsigned short)0x3F80 : (unsigned short)0;
    __syncthreads();
    unsigned short* outp = VT + (size_t)b * DD * SS;
    for (int i = 0; i < 4; ++i) {
        int id = (i << 8) + t;
        int n  = id >> 3;
        int c8 = id & 7;
        us8 o;
        for (int j = 0; j < 8; ++j) o[j] = tile[((c8 << 3) + j) * 136 + n];
        *reinterpret_cast<us8*>(&outp[(size_t)n * SS + k0 + (c8 << 3)]) = o;
    }
}

// ---------------------------------------------------------------------------
// fused: pass A (flash: S^T=K.Q^T, exp, PV + L-column via mask MFMA, write O),
//        pass B (recompute S^T bit-identically, write P = exp*mask*invL).
// grid 256 (1 block/CU), 256 thr (4 waves x 32 q-rows = 128 q-rows/block).
// ---------------------------------------------------------------------------
__global__ __launch_bounds__(256, 1) void fused_attn_kernel(
    const float* __restrict__ Q, const float* __restrict__ Kg,
    const unsigned short* __restrict__ VTg, const unsigned short* __restrict__ maskbf,
    const int* __restrict__ maskg, float* __restrict__ O, float* __restrict__ P)
{
    __shared__ unsigned short Ks[128 * 128];
    __shared__ unsigned short VTs[128 * 128];
    __shared__ unsigned short Ps[4 * 32 * 128];
    __shared__ unsigned short Ls[16 * 128];
    __shared__ float maskLds[SS];
    __shared__ float invLs[128];

    // XCD batch-grouping swizzle: each XCD owns 2 batches (L2-resident K/VT)
    const int id  = blockIdx.x;
    const int xcd = id & 7, jj = id >> 3;
    const int b   = (xcd << 1) + (jj >> 4);
    const int q0  = (jj & 15) << 7;

    const int t = threadIdx.x, lane = t & 63, w = t >> 6;
    const int lr = lane & 15, lg = lane >> 4;

    const float* Qg = Q + ((size_t)b * SS + q0) * DD;
    const float* Kb = Kg + (size_t)b * SS * DD;
    const unsigned short* Vb = VTg + (size_t)b * DD * SS;
    const unsigned short* Mb = maskbf + (size_t)b * SS;
    const int* mg = maskg + (size_t)b * SS;

    for (int i = t; i < 16 * 128; i += 256) Ls[i] = 0;
    for (int i = t; i < SS; i += 256) maskLds[i] = mg[i] ? 1.0f : 0.0f;

    // Q fragments (B-operand): lane holds q = 16m+lr, d = 32kb+8lg+j
    short8 qf[2][4];
    for (int m = 0; m < 2; ++m)
        for (int kb = 0; kb < 4; ++kb) {
            const float* qp = Qg + (size_t)(w * 32 + m * 16 + lr) * DD + kb * 32 + lg * 8;
            f32x4 a0 = *reinterpret_cast<const f32x4*>(qp);
            f32x4 a1 = *(reinterpret_cast<const f32x4*>(qp) + 1);
            short8 s;
            for (int j = 0; j < 4; ++j) { s[j] = (short)f2bf(a0[j]); s[4 + j] = (short)f2bf(a1[j]); }
            qf[m][kb] = s;
        }

    f32x4 oacc[2][8] = {};
    f32x4 lac[2] = {};
    f32x4 kreg[16];
    us8 vreg[8];
    us8 lsreg = {};

    // prefetch tile 0
    {
        const f32x4* kp = reinterpret_cast<const f32x4*>(Kb);
        for (int i = 0; i < 16; ++i) kreg[i] = kp[i * 256 + t];
        for (int i = 0; i < 8; ++i) {
            int fl = i * 256 + t;
            vreg[i] = *reinterpret_cast<const us8*>(Vb + (size_t)(fl >> 4) * SS + ((fl & 15) << 3));
        }
        if (t < 16) lsreg = *reinterpret_cast<const us8*>(Mb + t * 8);
    }

    unsigned short* Pw = &Ps[w * 4096];

    // ---------------- pass A ----------------
    for (int kt = 0; kt < NT; ++kt) {
        __syncthreads();
        // stage K (cvt), VT, maskrow from regs
        for (int i = 0; i < 16; ++i) {
            int f4 = i * 256 + t, row = f4 >> 5, col = (f4 & 31) << 2;
            us4 h;
            for (int j = 0; j < 4; ++j) h[j] = f2bf(kreg[i][j]);
            *reinterpret_cast<us4*>(&Ks[swzA(row, col)]) = h;
        }
        for (int i = 0; i < 8; ++i) {
            int fl = i * 256 + t;
            *reinterpret_cast<us8*>(&VTs[swzA(fl >> 4, (fl & 15) << 3)]) = vreg[i];
        }
        if (t < 16) *reinterpret_cast<us8*>(&Ls[swzA(0, t * 8)]) = lsreg;
        __syncthreads();
        // prefetch next tile
        if (kt + 1 < NT) {
            int kv1 = (kt + 1) << 7;
            const f32x4* kp = reinterpret_cast<const f32x4*>(Kb + (size_t)kv1 * DD);
            for (int i = 0; i < 16; ++i) kreg[i] = kp[i * 256 + t];
            for (int i = 0; i < 8; ++i) {
                int fl = i * 256 + t;
                vreg[i] = *reinterpret_cast<const us8*>(Vb + (size_t)(fl >> 4) * SS + kv1 + ((fl & 15) << 3));
            }
            if (t < 16) lsreg = *reinterpret_cast<const us8*>(Mb + kv1 + t * 8);
        }

        // S^T = K . Q^T : D col = q (lane&15), row = k (4lg+r)
        f32x4 sacc[2][8] = {};
        for (int kb = 0; kb < 4; ++kb) {
            short8 kf[8];
            for (int n = 0; n < 8; ++n)
                kf[n] = *reinterpret_cast<const short8*>(&Ks[swzA(n * 16 + lr, kb * 32 + lg * 8)]);
            for (int m = 0; m < 2; ++m)
                for (int n = 0; n < 8; ++n)
                    sacc[m][n] = __builtin_amdgcn_mfma_f32_16x16x32_bf16(
                        kf[n], qf[m][kb], sacc[m][n], 0, 0, 0);
        }

        // p = exp(s/scale) (UNMASKED; mask folded into VT + L-column), stash P[q][k]
        for (int m = 0; m < 2; ++m)
            for (int n = 0; n < 8; ++n) {
                us4 h;
                for (int r = 0; r < 4; ++r)
                    h[r] = f2bf(__expf(sacc[m][n][r] * INVSCALE));
                *reinterpret_cast<us4*>(&Pw[swzA(m * 16 + lr, n * 16 + lg * 4)]) = h;
            }

        // O += P*V (+ L-column): A = P[q][k], B = VT[d][k] / Ls
        for (int kb2 = 0; kb2 < 4; ++kb2) {
            short8 pf[2];
            for (int m = 0; m < 2; ++m)
                pf[m] = *reinterpret_cast<const short8*>(&Pw[swzA(m * 16 + lr, kb2 * 32 + lg * 8)]);
            short8 lsf = *reinterpret_cast<const short8*>(&Ls[swzA(lr, kb2 * 32 + lg * 8)]);
            for (int m = 0; m < 2; ++m)
                lac[m] = __builtin_amdgcn_mfma_f32_16x16x32_bf16(pf[m], lsf, lac[m], 0, 0, 0);
            for (int nd = 0; nd < 8; ++nd) {
                short8 vf = *reinterpret_cast<const short8*>(&VTs[swzA(nd * 16 + lr, kb2 * 32 + lg * 8)]);
                for (int m = 0; m < 2; ++m)
                    oacc[m][nd] = __builtin_amdgcn_mfma_f32_16x16x32_bf16(
                        pf[m], vf, oacc[m][nd], 0, 0, 0);
            }
        }
    }

    // prefetch pass-B tile 0 early (hides under epilogue)
    {
        const f32x4* kp = reinterpret_cast<const f32x4*>(Kb);
        for (int i = 0; i < 16; ++i) kreg[i] = kp[i * 256 + t];
    }

    // epilogue: invL, O write, invLs for pass B
    float* Og = O + ((size_t)b * SS + q0 + w * 32) * DD;
    for (int m = 0; m < 2; ++m) {
        if (lr == 0)
            for (int r = 0; r < 4; ++r) {
                float Lv = lac[m][r];
                invLs[w * 32 + m * 16 + lg * 4 + r] = Lv > 0.f ? 1.f / Lv : 0.f;
            }
        f32x4 inv;
        for (int r = 0; r < 4; ++r) {
            float Lv = __shfl(lac[m][r], lane & 48, 64);  // broadcast from lr==0 of this lg
            inv[r] = Lv > 0.f ? 1.f / Lv : 0.f;
        }
        for (int nd = 0; nd < 8; ++nd)
            for (int r = 0; r < 4; ++r)
                Og[(size_t)(m * 16 + lg * 4 + r) * DD + nd * 16 + lr] = oacc[m][nd][r] * inv[r];
    }
    __syncthreads();

    float il[2];
    for (int m = 0; m < 2; ++m) il[m] = invLs[w * 32 + m * 16 + lr];

    // ---------------- pass B ----------------
    for (int kt = 0; kt < NT; ++kt) {
        __syncthreads();
        for (int i = 0; i < 16; ++i) {
            int f4 = i * 256 + t, row = f4 >> 5, col = (f4 & 31) << 2;
            us4 h;
            for (int j = 0; j < 4; ++j) h[j] = f2bf(kreg[i][j]);
            *reinterpret_cast<us4*>(&Ks[swzA(row, col)]) = h;
        }
        __syncthreads();
        if (kt + 1 < NT) {
            const f32x4* kp = reinterpret_cast<const f32x4*>(Kb + (size_t)((kt + 1) << 7) * DD);
            for (int i = 0; i < 16; ++i) kreg[i] = kp[i * 256 + t];
        }

        f32x4 sacc[2][8] = {};
        for (int kb = 0; kb < 4; ++kb) {
            short8 kf[8];
            for (int n = 0; n < 8; ++n)
                kf[n] = *reinterpret_cast<const short8*>(&Ks[swzA(n * 16 + lr, kb * 32 + lg * 8)]);
            for (int m = 0; m < 2; ++m)
                for (int n = 0; n < 8; ++n)
                    sacc[m][n] = __builtin_amdgcn_mfma_f32_16x16x32_bf16(
                        kf[n], qf[m][kb], sacc[m][n], 0, 0, 0);
        }

        for (int m = 0; m < 2; ++m) {
            float* pr0 = P + ((size_t)b * SS + q0 + w * 32 + m * 16 + lr) * SS + (kt << 7);
            for (int n = 0; n < 8; ++n) {
                f32x4 mv = *reinterpret_cast<const f32x4*>(&maskLds[(kt << 7) + n * 16 + lg * 4]);
                f32x4 out;
                for (int r = 0; r < 4; ++r)
                    out[r] = __expf(sacc[m][n][r] * INVSCALE) * mv[r] * il[m];
                __builtin_nontemporal_store(out, reinterpret_cast<f32x4*>(pr0 + n * 16 + lg * 4));
            }
        }
    }
}

// ---------------------------------------------------------------------------
// Fallback pipeline (no workspace): round-2 kernels
// ---------------------------------------------------------------------------
__global__ __launch_bounds__(256) void qk_exp_kernel(
    const float* __restrict__ Q, const float* __restrict__ Kin,
    const int* __restrict__ mask, float* __restrict__ P)
{
    __shared__ unsigned short Qs[128 * 128];
    __shared__ unsigned short Ks[128 * 128];
    const int b  = blockIdx.z;
    const int m0 = blockIdx.y << 7;
    const int n0 = blockIdx.x << 7;
    const int t  = threadIdx.x;
    const float* Qp = Q   + ((size_t)b * SS + m0) * DD;
    const float* Kp = Kin + ((size_t)b * SS + n0) * DD;
    for (int i = 0; i < 16; ++i) {
        int f4  = (i << 8) + t;
        int row = f4 >> 5;
        int col = (f4 & 31) << 2;
        f32x4 q = reinterpret_cast<const f32x4*>(Qp)[f4];
        f32x4 k = reinterpret_cast<const f32x4*>(Kp)[f4];
        us4 qh, kh;
        for (int j = 0; j < 4; ++j) { qh[j] = f2bf(q[j]); kh[j] = f2bf(k[j]); }
        *reinterpret_cast<us4*>(&Qs[swzA(row, col)]) = qh;
        *reinterpret_cast<us4*>(&Ks[swzA(row, col)]) = kh;
    }
    __syncthreads();
    const int lane = t & 63, wid = t >> 6;
    const int wr = wid >> 1, wc = wid & 1;
    const int lr = lane & 15, lg = lane >> 4;
    f32x4 acc[4][4] = {};
    for (int kb = 0; kb < 4; ++kb) {
        short8 a[4], bq[4];
        int kcol = (kb << 5) + (lg << 3);
        for (int m = 0; m < 4; ++m)
            a[m] = *reinterpret_cast<const short8*>(&Qs[swzA((wr << 6) + (m << 4) + lr, kcol)]);
        for (int n = 0; n < 4; ++n)
            bq[n] = *reinterpret_cast<const short8*>(&Ks[swzA((wc << 6) + (n << 4) + lr, kcol)]);
        for (int m = 0; m < 4; ++m)
            for (int n = 0; n < 4; ++n)
                acc[m][n] = __builtin_amdgcn_mfma_f32_16x16x32_bf16(a[m], bq[n], acc[m][n], 0, 0, 0);
    }
    const int* am = mask + (size_t)b * SS;
    for (int n = 0; n < 4; ++n) {
        int col = n0 + (wc << 6) + (n << 4) + lr;
        bool allow = am[col] != 0;
        for (int m = 0; m < 4; ++m) {
            int rowb = m0 + (wr << 6) + (m << 4) + (lg << 2);
            float* Pp = P + ((size_t)b * SS + rowb) * SS + col;
            for (int r = 0; r < 4; ++r) {
                float p = allow ? __expf(acc[m][n][r] * INVSCALE) : 0.0f;
                Pp[(size_t)r * SS] = p;
            }
        }
    }
}

__global__ __launch_bounds__(256) void norm_kernel(float* __restrict__ P)
{
    int row  = (blockIdx.x << 2) + (threadIdx.x >> 6);
    int lane = threadIdx.x & 63;
    float* Pr = P + (size_t)row * SS;
    f32x4 v[8];
    float sum = 0.f;
    for (int i = 0; i < 8; ++i) {
        v[i] = reinterpret_cast<f32x4*>(Pr)[(i << 6) + lane];
        sum += v[i][0] + v[i][1] + v[i][2] + v[i][3];
    }
    for (int off = 1; off < 64; off <<= 1) sum += __shfl_xor(sum, off, 64);
    float inv = sum > 0.f ? 1.f / sum : 0.f;
    for (int i = 0; i < 8; ++i) {
        f32x4 wv = v[i];
        for (int j = 0; j < 4; ++j) wv[j] *= inv;
        reinterpret_cast<f32x4*>(Pr)[(i << 6) + lane] = wv;
    }
}

__global__ __launch_bounds__(256) void pv_fallback_kernel(
    const float* __restrict__ P, const float* __restrict__ V, float* __restrict__ O)
{
    __shared__ unsigned short Ws[64 * 64];
    const int b  = blockIdx.y;
    const int m0 = blockIdx.x << 6;
    const int t  = threadIdx.x, lane = t & 63, wid = t >> 6;
    const int wr = wid >> 1, wc = wid & 1;
    const int lr = lane & 15, lg = lane >> 4;
    const float* Pg = P + ((size_t)b * SS + m0) * SS;
    f32x4 acc[2][4] = {};
    for (int k0 = 0; k0 < SS; k0 += 64) {
        __syncthreads();
        for (int i = 0; i < 4; ++i) {
            int f4  = (i << 8) + t;
            int row = f4 >> 4;
            int col = (f4 & 15) << 2;
            f32x4 wv = *reinterpret_cast<const f32x4*>(Pg + (size_t)row * SS + k0 + col);
            us4 h;
            for (int j = 0; j < 4; ++j) h[j] = f2bf(wv[j]);
            *reinterpret_cast<us4*>(&Ws[swzB(row, col)]) = h;
        }
        __syncthreads();
        for (int kk = 0; kk < 64; kk += 32) {
            short8 a[2], bv[4];
            int kcol = kk + (lg << 3);
            for (int m = 0; m < 2; ++m)
                a[m] = *reinterpret_cast<const short8*>(&Ws[swzB((wr << 5) + (m << 4) + lr, kcol)]);
            for (int n = 0; n < 4; ++n) {
                int col = (wc << 6) + (n << 4) + lr;
                const float* vp = V + ((size_t)b * SS + k0 + kcol) * DD + col;
                short8 x;
                for (int j = 0; j < 8; ++j) x[j] = (short)f2bf(vp[(size_t)j * DD]);
                bv[n] = x;
            }
            for (int m = 0; m < 2; ++m)
                for (int n = 0; n < 4; ++n)
                    acc[m][n] = __builtin_amdgcn_mfma_f32_16x16x32_bf16(a[m], bv[n], acc[m][n], 0, 0, 0);
        }
    }
    float* Og = O + ((size_t)b * SS + m0) * DD;
    for (int m = 0; m < 2; ++m)
        for (int n = 0; n < 4; ++n)
            for (int r = 0; r < 4; ++r)
                Og[(size_t)((wr << 5) + (m << 4) + (lg << 2) + r) * DD
                   + (wc << 6) + (n << 4) + lr] = acc[m][n][r];
}

// ---------------------------------------------------------------------------
extern "C" void kernel_launch(void* const* d_in, const int* in_sizes, int n_in,
                              void* d_out, int out_size, void* d_ws, size_t ws_size,
                              hipStream_t stream)
{
    const float* Q  = (const float*)d_in[0];
    const float* K  = (const float*)d_in[1];
    const float* V  = (const float*)d_in[2];
    const int* mask = (const int*)d_in[3];
    float* O = (float*)d_out;
    float* P = O + (size_t)BB * SS * DD;

    const size_t nV   = (size_t)BB * SS * DD;  // elements
    const size_t need = (nV + (size_t)BB * SS) * sizeof(unsigned short);

    if (ws_size >= need) {
        unsigned short* VT     = (unsigned short*)d_ws;
        unsigned short* maskbf = VT + nV;
        vt_kernel<<<dim3(SS / 64, BB), 256, 0, stream>>>(V, mask, VT, maskbf);
        fused_attn_kernel<<<256, 256, 0, stream>>>(Q, K, VT, maskbf, mask, O, P);
    } else {
        qk_exp_kernel<<<dim3(SS / 128, SS / 128, BB), 256, 0, stream>>>(Q, K, mask, P);
        norm_kernel<<<(BB * SS) / 4, 256, 0, stream>>>(P);
        pv_fallback_kernel<<<dim3(SS / 64, BB), 256, 0, stream>>>(P, V, O);
    }
}

// Round 4
// 176.258 us; speedup vs baseline: 1.5576x; 1.0294x over previous
//
#include <hip/hip_runtime.h>

#define BB 16
#define SS 2048
#define DD 128
#define NT (SS / 128)                  // 16 KV tiles of 128
#define INVSCALE 0.08838834764831845f  // 1/sqrt(128)

typedef __attribute__((ext_vector_type(4))) float f32x4;
typedef __attribute__((ext_vector_type(8))) short short8;
typedef __attribute__((ext_vector_type(4))) unsigned short us4;
typedef __attribute__((ext_vector_type(8))) unsigned short us8;

__device__ inline unsigned short f2bf(float f) {
    unsigned u = __float_as_uint(f);
    u += 0x7fffu + ((u >> 16) & 1u);   // round-to-nearest-even
    return (unsigned short)(u >> 16);
}

// XOR swizzle for bf16 LDS tiles with 128-col (256 B) rows
__device__ inline int swzA(int row, int col) {
    int byteoff = (row << 8) + ((col >> 3) << 4);
    byteoff ^= (row & 7) << 4;
    return (byteoff >> 1) + (col & 7);
}
__device__ inline int swzB(int row, int col) { // 64-col (128 B) rows
    int byteoff = (row << 7) + ((col >> 3) << 4);
    byteoff ^= (row & 7) << 4;
    return (byteoff >> 1) + (col & 7);
}

// ---------------------------------------------------------------------------
// conv: Q,K fp32 -> bf16; mask int -> bf16 (1.0/0.0)
// ---------------------------------------------------------------------------
__global__ __launch_bounds__(256) void conv_bf16_kernel(
    const float* __restrict__ Q, const float* __restrict__ K,
    const int* __restrict__ mask,
    unsigned short* __restrict__ Qb, unsigned short* __restrict__ Kb,
    unsigned short* __restrict__ maskbf)
{
    int idx = blockIdx.x * blockDim.x + threadIdx.x;
    const int total = BB * SS * DD / 4;
    for (int i = idx; i < total; i += gridDim.x * blockDim.x) {
        f32x4 q = reinterpret_cast<const f32x4*>(Q)[i];
        f32x4 k = reinterpret_cast<const f32x4*>(K)[i];
        us4 qh, kh;
        for (int j = 0; j < 4; ++j) { qh[j] = f2bf(q[j]); kh[j] = f2bf(k[j]); }
        reinterpret_cast<us4*>(Qb)[i] = qh;
        reinterpret_cast<us4*>(Kb)[i] = kh;
    }
    if (idx < BB * SS)
        maskbf[idx] = mask[idx] ? (unsigned short)0x3F80 : (unsigned short)0;
}

// ---------------------------------------------------------------------------
// vt: V (b,k,d) fp32 -> VT (b,d,k) bf16 (unmasked; mask applied to P)
// ---------------------------------------------------------------------------
__global__ __launch_bounds__(256) void vt_kernel(
    const float* __restrict__ V, unsigned short* __restrict__ VT)
{
    __shared__ unsigned short tile[64 * 136];
    int b = blockIdx.y, k0 = blockIdx.x << 6;
    int t = threadIdx.x;
    const float* Vg = V + ((size_t)b * SS + k0) * DD;
    for (int i = 0; i < 8; ++i) {
        int f4 = (i << 8) + t;
        int k  = f4 >> 5;
        int n  = (f4 & 31) << 2;
        f32x4 v = reinterpret_cast<const f32x4*>(Vg)[f4];
        us4 h;
        for (int j = 0; j < 4; ++j) h[j] = f2bf(v[j]);
        *reinterpret_cast<us4*>(&tile[k * 136 + n]) = h;
    }
    __syncthreads();
    unsigned short* outp = VT + (size_t)b * DD * SS;
    for (int i = 0; i < 4; ++i) {
        int id = (i << 8) + t;
        int n  = id >> 3;
        int c8 = id & 7;
        us8 o;
        for (int j = 0; j < 8; ++j) o[j] = tile[((c8 << 3) + j) * 136 + n];
        *reinterpret_cast<us8*>(&outp[(size_t)n * SS + k0 + (c8 << 3)]) = o;
    }
}

// ---------------------------------------------------------------------------
// flashA: O and invL. grid 512 (2 blocks/CU), 256 thr, 4 waves x 16 q-rows.
// Per tile: stage K+VT (reg prefetch, T14), S^T = K.Q^T, p = exp*mask (in-reg
// rowsum), P->LDS (wave-local, 2 halves), O += P*V. Epilogue scales by invL.
// ---------------------------------------------------------------------------
__global__ __launch_bounds__(256, 2) void flashA_kernel(
    const unsigned short* __restrict__ Qb, const unsigned short* __restrict__ Kb,
    const unsigned short* __restrict__ VT, const unsigned short* __restrict__ maskbf,
    float* __restrict__ O, float* __restrict__ invLg)
{
    __shared__ unsigned short Ks[128 * 128];
    __shared__ unsigned short VTs[128 * 128];
    __shared__ unsigned short Ps[4 * 16 * 64];

    const int id = blockIdx.x, xcd = id & 7, j = id >> 3;  // grid 512
    const int b  = (xcd << 1) + (j >> 5);
    const int q0 = (j & 31) << 6;
    const int t = threadIdx.x, lane = t & 63, w = t >> 6;
    const int lr = lane & 15, lg = lane >> 4;

    const unsigned short* Kbb = Kb + (size_t)b * SS * DD;
    const unsigned short* Vbb = VT + (size_t)b * DD * SS;
    const unsigned short* Mbb = maskbf + (size_t)b * SS;

    // Q fragments (B-operand), q = q0 + w*16 + lr
    const unsigned short* Qp = Qb + ((size_t)b * SS + q0 + w * 16 + lr) * DD;
    short8 qf[4];
    for (int kb = 0; kb < 4; ++kb)
        qf[kb] = *reinterpret_cast<const short8*>(Qp + kb * 32 + lg * 8);

    f32x4 oacc[8] = {};
    float rsum = 0.f;

    us8 kstg[8], vstg[8];
    for (int i = 0; i < 8; ++i) {
        int f = i * 256 + t, row = f >> 4, col = (f & 15) << 3;
        kstg[i] = *reinterpret_cast<const us8*>(Kbb + (size_t)row * DD + col);
        vstg[i] = *reinterpret_cast<const us8*>(Vbb + (size_t)row * SS + col);
    }
    unsigned short* Pw = &Ps[w * 1024];

    for (int kt = 0; kt < NT; ++kt) {
        __syncthreads();   // all waves done reading previous tile
        for (int i = 0; i < 8; ++i) {
            int f = i * 256 + t, row = f >> 4, col = (f & 15) << 3;
            *reinterpret_cast<us8*>(&Ks[swzA(row, col)])  = kstg[i];
            *reinterpret_cast<us8*>(&VTs[swzA(row, col)]) = vstg[i];
        }
        __syncthreads();
        if (kt + 1 < NT) {   // T14: issue next-tile loads, consumed next iter
            int base = (kt + 1) << 7;
            for (int i = 0; i < 8; ++i) {
                int f = i * 256 + t, row = f >> 4, col = (f & 15) << 3;
                kstg[i] = *reinterpret_cast<const us8*>(Kbb + (size_t)(base + row) * DD + col);
                vstg[i] = *reinterpret_cast<const us8*>(Vbb + (size_t)row * SS + base + col);
            }
        }

        // S^T = K . Q^T : col = q = lr, row-within-16 = 4lg + r
        f32x4 sacc[8] = {};
        for (int kb = 0; kb < 4; ++kb)
            for (int n = 0; n < 8; ++n) {
                short8 kf = *reinterpret_cast<const short8*>(&Ks[swzA(n * 16 + lr, kb * 32 + lg * 8)]);
                sacc[n] = __builtin_amdgcn_mfma_f32_16x16x32_bf16(kf, qf[kb], sacc[n], 0, 0, 0);
            }

        // two k-halves: exp*mask -> rowsum + bf16 pack -> wave-local LDS -> PV
        for (int h = 0; h < 2; ++h) {
            for (int nl = 0; nl < 4; ++nl) {
                int n = h * 4 + nl;
                us4 mb = *reinterpret_cast<const us4*>(Mbb + (kt << 7) + n * 16 + lg * 4);
                us4 hh;
                for (int r = 0; r < 4; ++r) {
                    float mf = __uint_as_float((unsigned)mb[r] << 16);
                    float p  = __expf(sacc[n][r] * INVSCALE) * mf;
                    rsum += p;
                    hh[r] = f2bf(p);
                }
                *reinterpret_cast<us4*>(&Pw[swzB(lr, nl * 16 + lg * 4)]) = hh;
            }
            asm volatile("s_waitcnt lgkmcnt(0)" ::: "memory");
            __builtin_amdgcn_sched_barrier(0);
            for (int k2 = 0; k2 < 2; ++k2) {
                short8 pf = *reinterpret_cast<const short8*>(&Pw[swzB(lr, k2 * 32 + lg * 8)]);
                for (int nd = 0; nd < 8; ++nd) {
                    short8 vf = *reinterpret_cast<const short8*>(
                        &VTs[swzA(nd * 16 + lr, h * 64 + k2 * 32 + lg * 8)]);
                    oacc[nd] = __builtin_amdgcn_mfma_f32_16x16x32_bf16(pf, vf, oacc[nd], 0, 0, 0);
                }
            }
        }
    }

    // L reduce across the 4 lanes sharing lr (lg groups)
    rsum += __shfl_xor(rsum, 16, 64);
    rsum += __shfl_xor(rsum, 32, 64);
    if (lane < 16) {   // lg==0, lr==lane
        float iv = rsum > 0.f ? 1.f / rsum : 0.f;
        invLg[(size_t)b * SS + q0 + w * 16 + lr] = iv;
    }
    f32x4 inv;
    for (int r = 0; r < 4; ++r) {
        float Lq = __shfl(rsum, 4 * lg + r, 64);   // lane 4lg+r has lr==4lg+r
        inv[r] = Lq > 0.f ? 1.f / Lq : 0.f;
    }
    float* Og = O + ((size_t)b * SS + q0 + w * 16) * DD;
    for (int nd = 0; nd < 8; ++nd)
        for (int r = 0; r < 4; ++r)
            Og[(size_t)(4 * lg + r) * DD + nd * 16 + lr] = oacc[nd][r] * inv[r];
}

// ---------------------------------------------------------------------------
// pstoreB: recompute S^T bit-identically, write P = exp*mask*invL (fp32).
// grid 1024 (4 blocks/CU), 128 thr, 2 waves x 16 q-rows. LDS = Ks only.
// ---------------------------------------------------------------------------
__global__ __launch_bounds__(128, 2) void pstoreB_kernel(
    const unsigned short* __restrict__ Qb, const unsigned short* __restrict__ Kb,
    const unsigned short* __restrict__ maskbf, const float* __restrict__ invLg,
    float* __restrict__ P)
{
    __shared__ unsigned short Ks[128 * 128];

    const int id = blockIdx.x, xcd = id & 7, j = id >> 3;  // grid 1024
    const int b  = (xcd << 1) + (j >> 6);
    const int q0 = (j & 63) << 5;
    const int t = threadIdx.x, lane = t & 63, w = t >> 6;
    const int lr = lane & 15, lg = lane >> 4;

    const unsigned short* Kbb = Kb + (size_t)b * SS * DD;
    const unsigned short* Mbb = maskbf + (size_t)b * SS;

    const unsigned short* Qp = Qb + ((size_t)b * SS + q0 + w * 16 + lr) * DD;
    short8 qf[4];
    for (int kb = 0; kb < 4; ++kb)
        qf[kb] = *reinterpret_cast<const short8*>(Qp + kb * 32 + lg * 8);

    float il = invLg[(size_t)b * SS + q0 + w * 16 + lr];

    us8 kstg[16];
    for (int i = 0; i < 16; ++i) {
        int f = i * 128 + t, row = f >> 4, col = (f & 15) << 3;
        kstg[i] = *reinterpret_cast<const us8*>(Kbb + (size_t)row * DD + col);
    }

    for (int kt = 0; kt < NT; ++kt) {
        __syncthreads();
        for (int i = 0; i < 16; ++i) {
            int f = i * 128 + t, row = f >> 4, col = (f & 15) << 3;
            *reinterpret_cast<us8*>(&Ks[swzA(row, col)]) = kstg[i];
        }
        __syncthreads();
        if (kt + 1 < NT) {
            int base = (kt + 1) << 7;
            for (int i = 0; i < 16; ++i) {
                int f = i * 128 + t, row = f >> 4, col = (f & 15) << 3;
                kstg[i] = *reinterpret_cast<const us8*>(Kbb + (size_t)(base + row) * DD + col);
            }
        }

        // identical structure/order to flashA -> bit-identical sacc
        f32x4 sacc[8] = {};
        for (int kb = 0; kb < 4; ++kb)
            for (int n = 0; n < 8; ++n) {
                short8 kf = *reinterpret_cast<const short8*>(&Ks[swzA(n * 16 + lr, kb * 32 + lg * 8)]);
                sacc[n] = __builtin_amdgcn_mfma_f32_16x16x32_bf16(kf, qf[kb], sacc[n], 0, 0, 0);
            }

        float* Pp = P + ((size_t)b * SS + q0 + w * 16 + lr) * SS + (kt << 7);
        for (int n = 0; n < 8; ++n) {
            us4 mb = *reinterpret_cast<const us4*>(Mbb + (kt << 7) + n * 16 + lg * 4);
            f32x4 out;
            for (int r = 0; r < 4; ++r) {
                float mf = __uint_as_float((unsigned)mb[r] << 16);
                out[r] = __expf(sacc[n][r] * INVSCALE) * mf * il;
            }
            *reinterpret_cast<f32x4*>(Pp + n * 16 + lg * 4) = out;
        }
    }
}

// ---------------------------------------------------------------------------
// Fallback pipeline (no workspace requirements): round-1 kernels
// ---------------------------------------------------------------------------
__global__ __launch_bounds__(256) void qk_exp_kernel(
    const float* __restrict__ Q, const float* __restrict__ Kin,
    const int* __restrict__ mask, float* __restrict__ P)
{
    __shared__ unsigned short Qs[128 * 128];
    __shared__ unsigned short Ks[128 * 128];
    const int b  = blockIdx.z;
    const int m0 = blockIdx.y << 7;
    const int n0 = blockIdx.x << 7;
    const int t  = threadIdx.x;
    const float* Qp = Q   + ((size_t)b * SS + m0) * DD;
    const float* Kp = Kin + ((size_t)b * SS + n0) * DD;
    for (int i = 0; i < 16; ++i) {
        int f4  = (i << 8) + t;
        int row = f4 >> 5;
        int col = (f4 & 31) << 2;
        f32x4 q = reinterpret_cast<const f32x4*>(Qp)[f4];
        f32x4 k = reinterpret_cast<const f32x4*>(Kp)[f4];
        us4 qh, kh;
        for (int jj = 0; jj < 4; ++jj) { qh[jj] = f2bf(q[jj]); kh[jj] = f2bf(k[jj]); }
        *reinterpret_cast<us4*>(&Qs[swzA(row, col)]) = qh;
        *reinterpret_cast<us4*>(&Ks[swzA(row, col)]) = kh;
    }
    __syncthreads();
    const int lane = t & 63, wid = t >> 6;
    const int wr = wid >> 1, wc = wid & 1;
    const int lr = lane & 15, lg = lane >> 4;
    f32x4 acc[4][4] = {};
    for (int kb = 0; kb < 4; ++kb) {
        short8 a[4], bq[4];
        int kcol = (kb << 5) + (lg << 3);
        for (int m = 0; m < 4; ++m)
            a[m] = *reinterpret_cast<const short8*>(&Qs[swzA((wr << 6) + (m << 4) + lr, kcol)]);
        for (int n = 0; n < 4; ++n)
            bq[n] = *reinterpret_cast<const short8*>(&Ks[swzA((wc << 6) + (n << 4) + lr, kcol)]);
        for (int m = 0; m < 4; ++m)
            for (int n = 0; n < 4; ++n)
                acc[m][n] = __builtin_amdgcn_mfma_f32_16x16x32_bf16(a[m], bq[n], acc[m][n], 0, 0, 0);
    }
    const int* am = mask + (size_t)b * SS;
    for (int n = 0; n < 4; ++n) {
        int col = n0 + (wc << 6) + (n << 4) + lr;
        bool allow = am[col] != 0;
        for (int m = 0; m < 4; ++m) {
            int rowb = m0 + (wr << 6) + (m << 4) + (lg << 2);
            float* Pp = P + ((size_t)b * SS + rowb) * SS + col;
            for (int r = 0; r < 4; ++r) {
                float p = allow ? __expf(acc[m][n][r] * INVSCALE) : 0.0f;
                Pp[(size_t)r * SS] = p;
            }
        }
    }
}

__global__ __launch_bounds__(256) void norm_kernel(float* __restrict__ P)
{
    int row  = (blockIdx.x << 2) + (threadIdx.x >> 6);
    int lane = threadIdx.x & 63;
    float* Pr = P + (size_t)row * SS;
    f32x4 v[8];
    float sum = 0.f;
    for (int i = 0; i < 8; ++i) {
        v[i] = reinterpret_cast<f32x4*>(Pr)[(i << 6) + lane];
        sum += v[i][0] + v[i][1] + v[i][2] + v[i][3];
    }
    for (int off = 1; off < 64; off <<= 1) sum += __shfl_xor(sum, off, 64);
    float inv = sum > 0.f ? 1.f / sum : 0.f;
    for (int i = 0; i < 8; ++i) {
        f32x4 wv = v[i];
        for (int jj = 0; jj < 4; ++jj) wv[jj] *= inv;
        reinterpret_cast<f32x4*>(Pr)[(i << 6) + lane] = wv;
    }
}

__global__ __launch_bounds__(256) void pv_fallback_kernel(
    const float* __restrict__ P, const float* __restrict__ V, float* __restrict__ O)
{
    __shared__ unsigned short Ws[64 * 64];
    const int b  = blockIdx.y;
    const int m0 = blockIdx.x << 6;
    const int t  = threadIdx.x, lane = t & 63, wid = t >> 6;
    const int wr = wid >> 1, wc = wid & 1;
    const int lr = lane & 15, lg = lane >> 4;
    const float* Pg = P + ((size_t)b * SS + m0) * SS;
    f32x4 acc[2][4] = {};
    for (int k0 = 0; k0 < SS; k0 += 64) {
        __syncthreads();
        for (int i = 0; i < 4; ++i) {
            int f4  = (i << 8) + t;
            int row = f4 >> 4;
            int col = (f4 & 15) << 2;
            f32x4 wv = *reinterpret_cast<const f32x4*>(Pg + (size_t)row * SS + k0 + col);
            us4 h;
            for (int jj = 0; jj < 4; ++jj) h[jj] = f2bf(wv[jj]);
            *reinterpret_cast<us4*>(&Ws[swzB(row, col)]) = h;
        }
        __syncthreads();
        for (int kk = 0; kk < 64; kk += 32) {
            short8 a[2], bv[4];
            int kcol = kk + (lg << 3);
            for (int m = 0; m < 2; ++m)
                a[m] = *reinterpret_cast<const short8*>(&Ws[swzB((wr << 5) + (m << 4) + lr, kcol)]);
            for (int n = 0; n < 4; ++n) {
                int col = (wc << 6) + (n << 4) + lr;
                const float* vp = V + ((size_t)b * SS + k0 + kcol) * DD + col;
                short8 x;
                for (int jj = 0; jj < 8; ++jj) x[jj] = (short)f2bf(vp[(size_t)jj * DD]);
                bv[n] = x;
            }
            for (int m = 0; m < 2; ++m)
                for (int n = 0; n < 4; ++n)
                    acc[m][n] = __builtin_amdgcn_mfma_f32_16x16x32_bf16(a[m], bv[n], acc[m][n], 0, 0, 0);
        }
    }
    float* Og = O + ((size_t)b * SS + m0) * DD;
    for (int m = 0; m < 2; ++m)
        for (int n = 0; n < 4; ++n)
            for (int r = 0; r < 4; ++r)
                Og[(size_t)((wr << 5) + (m << 4) + (lg << 2) + r) * DD
                   + (wc << 6) + (n << 4) + lr] = acc[m][n][r];
}

// ---------------------------------------------------------------------------
extern "C" void kernel_launch(void* const* d_in, const int* in_sizes, int n_in,
                              void* d_out, int out_size, void* d_ws, size_t ws_size,
                              hipStream_t stream)
{
    const float* Q  = (const float*)d_in[0];
    const float* K  = (const float*)d_in[1];
    const float* V  = (const float*)d_in[2];
    const int* mask = (const int*)d_in[3];
    float* O = (float*)d_out;
    float* P = O + (size_t)BB * SS * DD;

    const size_t nE = (size_t)BB * SS * DD;   // elements per tensor
    const size_t need = 3 * nE * sizeof(unsigned short)
                      + (size_t)BB * SS * sizeof(unsigned short)
                      + (size_t)BB * SS * sizeof(float);

    if (ws_size >= need) {
        unsigned short* Qb     = (unsigned short*)d_ws;
        unsigned short* Kb     = Qb + nE;
        unsigned short* VT     = Kb + nE;
        unsigned short* maskbf = VT + nE;
        float* invLg = (float*)(maskbf + (size_t)BB * SS);

        conv_bf16_kernel<<<1024, 256, 0, stream>>>(Q, K, mask, Qb, Kb, maskbf);
        vt_kernel<<<dim3(SS / 64, BB), 256, 0, stream>>>(V, VT);
        flashA_kernel<<<512, 256, 0, stream>>>(Qb, Kb, VT, maskbf, O, invLg);
        pstoreB_kernel<<<1024, 128, 0, stream>>>(Qb, Kb, maskbf, invLg, P);
    } else {
        qk_exp_kernel<<<dim3(SS / 128, SS / 128, BB), 256, 0, stream>>>(Q, K, mask, P);
        norm_kernel<<<(BB * SS) / 4, 256, 0, stream>>>(P);
        pv_fallback_kernel<<<dim3(SS / 64, BB), 256, 0, stream>>>(P, V, O);
    }
}